// Round 1
// baseline (392.452 us; speedup 1.0000x reference)
//
#include <hip/hip_runtime.h>
#include <hip/hip_bf16.h>

typedef unsigned short ush;
typedef __bf16 v8bf __attribute__((ext_vector_type(8)));
typedef float f32x4 __attribute__((ext_vector_type(4)));

#define SPD 56           // input spatial dim
#define OSD 52           // output spatial dim
#define SP2 3136         // 56*56
#define SP3 175616       // 56^3
#define PITCH 36         // patch row pitch (bf16 elems) = 72B : 2-way-max banks, 8B aligned
#define N_A_ELEMS (2*125*64*32)   // 512000

// ---------------- kernel 1: build fused conv kernel A[cg][tau][o][c] (bf16) -------------
__global__ void build_A(const float* __restrict__ weight, const float* __restrict__ w_sc0,
                        const float* __restrict__ w_sc1, ush* __restrict__ A) {
    int f = blockIdx.x * 256 + threadIdx.x;
    if (f >= N_A_ELEMS) return;
    int c   = f & 31;
    int o   = (f >> 5) & 63;
    int t2  = f >> 11;            // cg*125 + tau
    int tau = t2 % 125;
    int cg  = t2 / 125;
    int i   = cg * 32 + c;        // input channel
    int dz = tau / 25, dy = (tau / 5) % 5, dx = tau % 5;
    float rz = -1.f + 0.5f * dz, ry = -1.f + 0.5f * dy, rx = -1.f + 0.5f * dx;
    float d = sqrtf(rz * rz + ry * ry + rx * rx);
    float dm = fmaxf(d, 1e-12f);
    float nv[3] = { rz / dm, ry / dm, rx / dm };
    float emb[5];
    #pragma unroll
    for (int m = 0; m < 5; m++) {
        float diff = 4.f * d - (float)m;
        float ta = diff + 1.f, tb = 1.f - diff;
        float sa = ta > 0.f ? expf(-1.f / ta) : 0.f;
        float sb = tb > 0.f ? expf(-1.f / tb) : 0.f;
        emb[m] = 1.14136f * 7.3890560989306495f * sa * sb;
    }
    const float PW0 = 0.17677669529663687f;  // sqrt(1/32)
    const float PW1 = 0.30618621784789724f;  // sqrt(3/32)
    const float IS3 = 0.57735026918962576f;  // 1/sqrt(3)
    float val = 0.f;
    int widx = -1; float scale = 0.f;
    if (i < 16) {
        if (o < 16) { widx = i * 16 + o;                         scale = PW0; }
        else        { int wc = (o - 16) / 3, kc = (o - 16) % 3;
                      widx = 256 + i * 16 + wc;                  scale = PW1 * nv[kc]; }
    } else {
        int u = (i - 16) / 3, ic = (i - 16) % 3;
        if (o < 16) { widx = 768 + u * 16 + o;                   scale = PW0 * nv[ic]; }
        else        { int wc = (o - 16) / 3, jc = (o - 16) % 3;
                      if (ic == jc) { widx = 512 + u * 16 + wc;  scale = PW1 * IS3; } }
    }
    if (widx >= 0) {
        float wv = 0.f;
        #pragma unroll
        for (int m = 0; m < 5; m++) wv += emb[m] * weight[m * 1024 + widx];
        val = scale * wv;
    }
    if (tau == 62) {  // center tap: fold sc (pointwise map, inv = 1/sqrt(16) = 0.25)
        if (i < 16 && o < 16) val += 0.25f * w_sc0[i * 16 + o];
        else if (i >= 16 && o >= 16) {
            int u = (i - 16) / 3, ic = (i - 16) % 3;
            int wc = (o - 16) / 3, jc = (o - 16) % 3;
            if (ic == jc) val += 0.25f * w_sc1[u * 16 + wc];
        }
    }
    __hip_bfloat16 b = __float2bfloat16(val);
    A[f] = *(ush*)&b;
}

// ---------------- kernel 2: x fp32 [c64][z][y][x] -> bf16 [cg2][z][y][x][c32] ----------
__global__ void conv_x(const float* __restrict__ x, ush* __restrict__ xb) {
    int lin = blockIdx.x * 256 + threadIdx.x;   // one 16B chunk (8 bf16)
    if (lin >= (2 * SP3 * 32) / 8) return;
    int e  = lin * 8;
    int c0 = e & 31;            // 0,8,16,24
    int V  = e >> 5;            // cg*SP3 + spatial
    int cg  = V / SP3;
    int rem = V % SP3;          // z*3136 + y*56 + x
    union { ush u[8]; uint4 v; } pk;
    #pragma unroll
    for (int j = 0; j < 8; j++) {
        int ch = cg * 32 + c0 + j;
        float v = x[ch * SP3 + rem];
        __hip_bfloat16 b = __float2bfloat16(v);
        pk.u[j] = *(ush*)&b;
    }
    *(uint4*)(xb + e) = pk.v;
}

// ---------------- kernel 3: main conv ---------------------------------------------------
// grid (13,13,13); block 128 threads = 2 waves. wave w: out-ch [w*32, w*32+32), all 64 px.
// tile (4,4,4) output voxels; patch (8,8,8) voxels x 32 ch per channel-group in LDS.
__launch_bounds__(128, 2)
__global__ void conv_main(const ush* __restrict__ A, const ush* __restrict__ xb,
                          float* __restrict__ out) {
    __shared__ ush patch[512 * PITCH];   // 36864 B

    const int tid  = threadIdx.x;
    const int wv   = tid >> 6;
    const int lane = tid & 63;
    const int n    = lane & 15;
    const int q    = lane >> 4;
    const int x0 = blockIdx.x * 4, y0 = blockIdx.y * 4, z0 = blockIdx.z * 4;

    // pixel p = nt*16 + n  ->  (z=nt, y=n>>2, x=n&3); patch row = z*64 + y*8 + x
    const int rbase = ((n >> 2) << 3) + (n & 3);

    // A fragment base: lane holds A[o = mbase + n][k = q*8 + j]
    const ush* Abase = A + (wv * 32 + n) * 32 + q * 8;

    f32x4 acc[2][4];
    #pragma unroll
    for (int mt = 0; mt < 2; mt++)
        #pragma unroll
        for (int nt = 0; nt < 4; nt++) {
            f32x4 z = {0.f, 0.f, 0.f, 0.f};
            acc[mt][nt] = z;
        }

    for (int cg = 0; cg < 2; cg++) {
        __syncthreads();
        // stage 512 voxels x 32ch: 2048 16B-units, 16 per thread
        #pragma unroll 4
        for (int it = 0; it < 16; it++) {
            int u   = tid + it * 128;
            int qq  = u & 3;
            int vox = u >> 2;
            int xp = vox & 7, yp = (vox >> 3) & 7, zp = vox >> 6;
            const ush* g = xb + (((cg * SPD + z0 + zp) * SPD + (y0 + yp)) * SPD + (x0 + xp)) * 32 + qq * 8;
            uint4 v = *(const uint4*)g;                 // 16B aligned
            ush* dst = patch + vox * PITCH + qq * 8;    // 72B pitch -> 8B aligned
            *(uint2*)dst       = make_uint2(v.x, v.y);
            *(uint2*)(dst + 4) = make_uint2(v.z, v.w);
        }
        __syncthreads();

        const ush* Ap = Abase + cg * 125 * 2048;
        for (int dz = 0; dz < 5; dz++)
            for (int dy = 0; dy < 5; dy++) {
                int rowdy = rbase + dz * 64 + dy * 8;
                #pragma unroll
                for (int dx = 0; dx < 5; dx++) {
                    v8bf a0 = *(const v8bf*)(Ap);
                    v8bf a1 = *(const v8bf*)(Ap + 512);   // +16 out-ch
                    Ap += 2048;
                    int row = rowdy + dx;
                    #pragma unroll
                    for (int nt = 0; nt < 4; nt++) {
                        const ush* bp = patch + (row + nt * 64) * PITCH + q * 8;
                        uint2 blo = *(const uint2*)bp;
                        uint2 bhi = *(const uint2*)(bp + 4);
                        union { unsigned int u[4]; v8bf v; } bb;
                        bb.u[0] = blo.x; bb.u[1] = blo.y; bb.u[2] = bhi.x; bb.u[3] = bhi.y;
                        acc[0][nt] = __builtin_amdgcn_mfma_f32_16x16x32_bf16(a0, bb.v, acc[0][nt], 0, 0, 0);
                        acc[1][nt] = __builtin_amdgcn_mfma_f32_16x16x32_bf16(a1, bb.v, acc[1][nt], 0, 0, 0);
                    }
                }
            }
    }

    // store: D row m = q*4 + r -> out-ch, col = n -> pixel
    #pragma unroll
    for (int mt = 0; mt < 2; mt++)
        #pragma unroll
        for (int nt = 0; nt < 4; nt++)
            #pragma unroll
            for (int r = 0; r < 4; r++) {
                int o  = wv * 32 + mt * 16 + q * 4 + r;
                int zz = z0 + nt, yy = y0 + (n >> 2), xx = x0 + (n & 3);
                out[((o * OSD + zz) * OSD + yy) * OSD + xx] = acc[mt][nt][r];
            }
}

extern "C" void kernel_launch(void* const* d_in, const int* in_sizes, int n_in,
                              void* d_out, int out_size, void* d_ws, size_t ws_size,
                              hipStream_t stream) {
    const float* x      = (const float*)d_in[0];
    const float* weight = (const float*)d_in[1];
    const float* w_sc0  = (const float*)d_in[2];
    const float* w_sc1  = (const float*)d_in[3];
    float* out = (float*)d_out;

    ush* A  = (ush*)d_ws;                               // 512000 elems = 1,024,000 B
    ush* xb = (ush*)((char*)d_ws + (1 << 20));          // 11,239,424 elems = 22.5 MB

    build_A<<<N_A_ELEMS / 256, 256, 0, stream>>>(weight, w_sc0, w_sc1, A);
    conv_x<<<(2 * SP3 * 32 / 8) / 256, 256, 0, stream>>>(x, xb);
    dim3 grid(13, 13, 13);
    conv_main<<<grid, 128, 0, stream>>>(A, xb, out);
}